// Round 1
// baseline (267.619 us; speedup 1.0000x reference)
//
#include <hip/hip_runtime.h>

// out[b,s,i*64+j] = max(x[b,s,i], kernel[i,j])
// B=8, S=2048, I=64, O=64. Output = 67,108,864 fp32 = 256 MiB. Pure write-bound.
//
// Layout facts (all powers of 2):
//   flat element e = ((row)*64 + i)*64 + j, row = b*S+s  (row in [0, 16384))
//   float4 index v = e/4:  row = v>>10, rem = v&1023, i = rem>>4, j4 = rem&15
//   kernel float4 index = i*16 + j4 = rem  -> LDS lookup kf[rem]

__global__ __launch_bounds__(256, 4) void fuzzy_max_kernel(
    const float* __restrict__ x,
    const float* __restrict__ km,
    float4* __restrict__ out,
    unsigned total4) {
  __shared__ float4 kf[1024];  // 16 KiB: the whole 64x64 kernel matrix

  const unsigned t = threadIdx.x;
  const float4* km4 = reinterpret_cast<const float4*>(km);
#pragma unroll
  for (int it = 0; it < 4; ++it) {
    kf[t + 256u * it] = km4[t + 256u * it];
  }
  __syncthreads();

  const unsigned stride = gridDim.x * blockDim.x;
  for (unsigned v = blockIdx.x * blockDim.x + t; v < total4; v += stride) {
    const unsigned row = v >> 10;        // which (b,s) row
    const unsigned rem = v & 1023u;      // position within the 4096-wide row
    const unsigned i = rem >> 4;         // input-feature index
    const float xv = x[(row << 6) | i];  // broadcast across 16 lanes, L1/L2 hot
    const float4 k = kf[rem];            // conflict-free ds_read_b128
    float4 o;
    o.x = fmaxf(xv, k.x);
    o.y = fmaxf(xv, k.y);
    o.z = fmaxf(xv, k.z);
    o.w = fmaxf(xv, k.w);
    out[v] = o;                          // coalesced 16 B/lane store
  }
}

extern "C" void kernel_launch(void* const* d_in, const int* in_sizes, int n_in,
                              void* d_out, int out_size, void* d_ws, size_t ws_size,
                              hipStream_t stream) {
  const float* x = reinterpret_cast<const float*>(d_in[0]);   // (8,2048,64) fp32
  const float* km = reinterpret_cast<const float*>(d_in[1]);  // (64,64) fp32
  float4* out = reinterpret_cast<float4*>(d_out);

  const unsigned total4 = (unsigned)(out_size / 4);  // 16,777,216 float4s
  const int block = 256;
  const int grid = 4096;  // grid-stride: ~16 float4/thread, LDS staging amortized
  fuzzy_max_kernel<<<grid, block, 0, stream>>>(x, km, out, total4);
}